// Round 19
// baseline (179.650 us; speedup 1.0000x reference)
//
#include <hip/hip_runtime.h>

typedef unsigned short u16;
typedef __bf16 bf16x8 __attribute__((ext_vector_type(8)));
typedef float f32x4 __attribute__((ext_vector_type(4)));
typedef float f32x16 __attribute__((ext_vector_type(16)));

#define DEV __device__ __forceinline__

constexpr int Bb = 4, Tt = 2048, Dd = 1024, Hh = 16, HDd = 64;
constexpr int MM = Bb * Tt;        // 8192
constexpr float QSCALE = 0.125f * 1.4426950408889634f;  // 1/sqrt(64) * log2(e)

DEV u16 f2bf(float f) {
  unsigned u = __float_as_uint(f);
  u += 0x7fffu + ((u >> 16) & 1u);   // RNE
  return (u16)(u >> 16);
}

DEV unsigned cvtpk(float a, float b) {   // bf16(a) in lo16, bf16(b) in hi16
  unsigned r;
  asm("v_cvt_pk_bf16_f32 %0, %1, %2" : "=v"(r) : "v"(a), "v"(b));
  return r;
}

DEV void pswap(unsigned& a, unsigned& b) {  // half-exchange across lane-32 split
  // NOTE: callers must pass values that are NOT provably equal (R4 NaN lesson).
  asm("v_permlane32_swap_b32 %0, %1" : "+v"(a), "+v"(b));
}

DEV void gload_lds16(const u16* g, u16* l) {
  __builtin_amdgcn_global_load_lds(
      (const __attribute__((address_space(1))) void*)g,
      (__attribute__((address_space(3))) void*)l, 16, 0, 0);
}

// ---------------- cast x -> bf16 ----------------
__global__ __launch_bounds__(256) void cast_x_kernel(const float* __restrict__ in,
                                                     u16* __restrict__ out, int n8) {
  int i = blockIdx.x * 256 + threadIdx.x;
  if (i >= n8) return;
  const float4* p = (const float4*)in + (size_t)i * 2;
  float4 v0 = p[0], v1 = p[1];
  union { u16 u[8]; uint4 v; } t;
  t.u[0] = f2bf(v0.x); t.u[1] = f2bf(v0.y); t.u[2] = f2bf(v0.z); t.u[3] = f2bf(v0.w);
  t.u[4] = f2bf(v1.x); t.u[5] = f2bf(v1.y); t.u[6] = f2bf(v1.z); t.u[7] = f2bf(v1.w);
  ((uint4*)out)[i] = t.v;
}

// ---------- cast + transpose weights: [K][N] f32 -> [N][K] bf16 ----------
__global__ __launch_bounds__(256) void wcast_t_kernel(const float* __restrict__ in,
                                                      u16* __restrict__ out, int K, int N) {
  __shared__ float tile[32][33];
  int n0 = blockIdx.x * 32, k0 = blockIdx.y * 32;
  int tx = threadIdx.x & 31, ty = threadIdx.x >> 5;
  #pragma unroll
  for (int yy = ty; yy < 32; yy += 8)
    tile[yy][tx] = in[(size_t)(k0 + yy) * N + n0 + tx];
  __syncthreads();
  #pragma unroll
  for (int yy = ty; yy < 32; yy += 8)
    out[(size_t)(n0 + yy) * K + k0 + tx] = f2bf(tile[tx][yy]);
}

// ======== 512-thread stager: 256 rows x 32 k half-tile (2 chunks/thread) ========
DEV void stageB256(const u16* __restrict__ src, int row0, int k0, int ld, u16* lds) {
  int t = threadIdx.x;              // 1024 chunks, 2 per thread
  #pragma unroll
  for (int j = 0; j < 2; ++j) {
    int e = j * 512 + t;
    int r = e >> 2, slot = e & 3;
    int c = (slot ^ ((r >> 1) & 3)) << 3;
    gload_lds16(src + (size_t)(row0 + r) * ld + k0 + c,
                lds + (size_t)(j * 512 + (t & ~63)) * 8);
  }
}

// ======== 256x256 QKV GEMM, 8-PHASE pipeline (T3+T4), 8 waves, 16x16 MFMA ========
// LDS 128KB: A[par][kh] @ par*16384 + kh*8192 u16 ; B same + 32768.
// Phases (kt-parity, row-half ch, k-half ksub); per phase: 8 ds_read_b128 ->
// 1 half-tile stage (2 gload_lds) -> barrier -> lgkmcnt(0) -> 16 MFMA -> bar.
// vmcnt(4) ONLY at phases 4 and 8 (2 newest stages stay in flight across
// barriers). Stage mapping issues each replacement >=1 phase after its slot's
// last reader; landed-ness hand-traced per half-tile (see session notes).
__global__ __launch_bounds__(512, 2) void gemm_qkv_kernel(
    const u16* __restrict__ A, const u16* __restrict__ Bt,
    const float* __restrict__ bias,
    u16* __restrict__ Qb, u16* __restrict__ Kb, u16* __restrict__ Vtb,
    int M, int N, int Kd) {
  __shared__ __align__(16) u16 SH[65536];   // 128 KB
  int nx = N >> 8;                           // 12
  int bid = blockIdx.y * nx + blockIdx.x;
  int nwg = (M >> 8) * nx;                   // 384 (%8==0)
  int swz = (bid & 7) * (nwg >> 3) + (bid >> 3);
  int m0 = (swz / nx) * 256, n0 = (swz % nx) * 256;

  int tid = threadIdx.x, l = tid & 63, w = tid >> 6;
  int lo = l & 15, g = l >> 4;
  int wr = w >> 2, wc = w & 3;               // 2 x 4 wave grid, per-wave 128x64
  f32x4 acc[8][4] = {};
  const int nkt = Kd >> 6;                   // 16 K-tiles of 64

  // prologue: kt0 both halves + kt1 kh0 (6 half-tiles, 12 loads), full drain.
  stageB256(A,  m0, 0,  Kd, SH);                       // A kt0 kh0 (par0)
  stageB256(Bt, n0, 0,  Kd, SH + 32768);
  stageB256(A,  m0, 32, Kd, SH + 8192);                // A kt0 kh1
  stageB256(Bt, n0, 32, Kd, SH + 32768 + 8192);
  stageB256(A,  m0, 64, Kd, SH + 16384);               // A kt1 kh0 (par1)
  stageB256(Bt, n0, 64, Kd, SH + 32768 + 16384);
  asm volatile("s_waitcnt vmcnt(0)" ::: "memory");
  __builtin_amdgcn_s_barrier();

#define QPHASE(PAR, CH, KS, STILE, SISB, SKH, DOW)                              \
  {                                                                             \
    const u16* Ab_ = SH + (PAR) * 16384 + (KS) * 8192;                          \
    const u16* Bb_ = SH + 32768 + (PAR) * 16384 + (KS) * 8192;                  \
    bf16x8 a_[4], b_[4];                                                        \
    _Pragma("unroll")                                                           \
    for (int i_ = 0; i_ < 4; ++i_) {                                            \
      int row = wr * 128 + (CH) * 64 + i_ * 16 + lo;                            \
      a_[i_] = *(const bf16x8*)&Ab_[row * 32 + ((g ^ ((row >> 1) & 3)) << 3)];  \
    }                                                                           \
    _Pragma("unroll")                                                           \
    for (int j_ = 0; j_ < 4; ++j_) {                                            \
      int row = wc * 64 + j_ * 16 + lo;                                         \
      b_[j_] = *(const bf16x8*)&Bb_[row * 32 + ((g ^ ((row >> 1) & 3)) << 3)];  \
    }                                                                           \
    if ((STILE) < nkt) {                                                        \
      if (SISB) stageB256(Bt, n0, (STILE) * 64 + (SKH) * 32, Kd,                \
                          SH + 32768 + ((STILE) & 1) * 16384 + (SKH) * 8192);   \
      else      stageB256(A,  m0, (STILE) * 64 + (SKH) * 32, Kd,                \
                          SH + ((STILE) & 1) * 16384 + (SKH) * 8192);           \
    }                                                                           \
    __builtin_amdgcn_s_barrier();                                               \
    asm volatile("s_waitcnt lgkmcnt(0)" ::: "memory");                          \
    __builtin_amdgcn_s_setprio(1);                                              \
    _Pragma("unroll")                                                           \
    for (int i_ = 0; i_ < 4; ++i_)                                              \
      _Pragma("unroll")                                                         \
      for (int j_ = 0; j_ < 4; ++j_)                                            \
        acc[(CH) * 4 + i_][j_] = __builtin_amdgcn_mfma_f32_16x16x32_bf16(       \
            a_[i_], b_[j_], acc[(CH) * 4 + i_][j_], 0, 0, 0);                   \
    __builtin_amdgcn_s_setprio(0);                                              \
    if (DOW) asm volatile("s_waitcnt vmcnt(4)" ::: "memory");                   \
    __builtin_amdgcn_s_barrier();                                               \
  }

  for (int t = 0; t < 8; ++t) {   // iteration = K-tiles 2t (par0), 2t+1 (par1)
    QPHASE(0, 0, 0, 2 * t + 1, 0, 1, 0);   // P1: stage A(2t+1)kh1
    QPHASE(0, 1, 0, 2 * t + 1, 1, 1, 0);   // P2: stage B(2t+1)kh1
    QPHASE(0, 0, 1, 2 * t + 2, 0, 0, 0);   // P3: stage A(2t+2)kh0
    QPHASE(0, 1, 1, 2 * t + 2, 1, 0, 1);   // P4: stage B(2t+2)kh0, vmcnt(4)
    QPHASE(1, 0, 0, 2 * t + 2, 0, 1, 0);   // P5: stage A(2t+2)kh1
    QPHASE(1, 1, 0, 2 * t + 2, 1, 1, 0);   // P6: stage B(2t+2)kh1
    QPHASE(1, 0, 1, 2 * t + 3, 0, 0, 0);   // P7: stage A(2t+3)kh0
    QPHASE(1, 1, 1, 2 * t + 3, 1, 0, 1);   // P8: stage B(2t+3)kh0, vmcnt(4)
  }
#undef QPHASE

  // ---- epilogue (R12-proven): per-wave 8KB patch, two 64-row halves ----
  asm volatile("s_waitcnt vmcnt(0)" ::: "memory");
  __builtin_amdgcn_s_barrier();
  u16* ep = SH + w * 4096;
  int nblk = n0 + wc * 64;
  int hh = nblk / 192, seg = (nblk % 192) >> 6;
  int mbase = m0 + wr * 128;
  int b_ = mbase >> 11;
  if (seg == 2) {
    // V: patch[d 0..63][t_local 0..63] (transposed) -> Vt[bh][d][t]
    u16* dst0 = Vtb + (size_t)(b_ * Hh + hh) * HDd * Tt;
    #pragma unroll
    for (int rh = 0; rh < 2; ++rh) {
      #pragma unroll
      for (int j = 0; j < 4; ++j) {
        float bv = bias[nblk + j * 16 + lo];
        int prow = j * 16 + lo;              // d
        #pragma unroll
        for (int ii = 0; ii < 4; ++ii) {
          int i = rh * 4 + ii;
          #pragma unroll
          for (int r = 0; r < 4; ++r) {
            int pcol = ii * 16 + g * 4 + r;  // t-local
            int slot = pcol >> 3;
            ep[prow * 64 + ((slot ^ (prow & 7)) << 3) + (pcol & 7)] =
                f2bf(acc[i][j][r] + bv);
          }
        }
      }
      asm volatile("s_waitcnt lgkmcnt(0)" ::: "memory");
      int t0 = (mbase + rh * 64) & (Tt - 1);
      #pragma unroll
      for (int s = 0; s < 8; ++s) {
        int row = s * 8 + (l >> 3);          // d
        int phys = ((l & 7) ^ (row & 7)) << 3;
        uint4 v = *(const uint4*)&ep[row * 64 + phys];
        *(uint4*)(dst0 + (size_t)row * Tt + t0 + (l & 7) * 8) = v;
      }
      asm volatile("s_waitcnt lgkmcnt(0)" ::: "memory");
    }
  } else {
    float qs = (seg == 0) ? QSCALE : 1.0f;
    u16* dstbase = ((seg == 0) ? Qb : Kb) + (size_t)(b_ * Hh + hh) * Tt * HDd;
    #pragma unroll
    for (int rh = 0; rh < 2; ++rh) {
      #pragma unroll
      for (int j = 0; j < 4; ++j) {
        float bv = bias[nblk + j * 16 + lo];
        int slot = j * 2 + (lo >> 3);
        #pragma unroll
        for (int ii = 0; ii < 4; ++ii) {
          int i = rh * 4 + ii;
          #pragma unroll
          for (int r = 0; r < 4; ++r) {
            int lrow = ii * 16 + g * 4 + r;  // t-local
            ep[lrow * 64 + ((slot ^ (lrow & 7)) << 3) + (lo & 7)] =
                f2bf((acc[i][j][r] + bv) * qs);
          }
        }
      }
      asm volatile("s_waitcnt lgkmcnt(0)" ::: "memory");
      int t0 = (mbase + rh * 64) & (Tt - 1);
      u16* dst = dstbase + (size_t)t0 * HDd;
      #pragma unroll
      for (int s = 0; s < 8; ++s) {
        int row = s * 8 + (l >> 3);          // t-local
        int phys = ((l & 7) ^ (row & 7)) << 3;
        uint4 v = *(const uint4*)&ep[row * 64 + phys];
        *(uint4*)(dst + row * 64 + (l & 7) * 8) = v;
      }
      asm volatile("s_waitcnt lgkmcnt(0)" ::: "memory");
    }
  }
}

// ---------------- 128x128 GEMM (out-proj): A[M][K] * Bt[N][K] -> f32 ----------------
DEV void stage_tile(const u16* __restrict__ src, int row0, int k0, int ld, u16* lds) {
  int t = threadIdx.x, w = t >> 6;
  #pragma unroll
  for (int j = 0; j < 2; ++j) {
    int e = (j * 256 + t) * 8;
    int r = e >> 5;
    int slot = (e >> 3) & 3;
    int c = (slot ^ ((r >> 1) & 3)) << 3;
    gload_lds16(src + (size_t)(row0 + r) * ld + k0 + c, lds + j * 2048 + w * 512);
  }
}

__global__ __launch_bounds__(256) void gemm_out_kernel(
    const u16* __restrict__ A, const u16* __restrict__ Bt,
    const float* __restrict__ bias, float* __restrict__ Cf,
    int M, int N, int Kd) {
  __shared__ __align__(16) u16 SH[24576];
  int nx = N >> 7;
  int bid = blockIdx.y * nx + blockIdx.x;
  int nwg = (M >> 7) * nx;
  int swz = (bid & 7) * (nwg >> 3) + (bid >> 3);
  int m0 = (swz / nx) * 128, n0 = (swz % nx) * 128;

  int tid = threadIdx.x, l = tid & 63, w = tid >> 6;
  int lo = l & 15, g = l >> 4;
  int wm = (w >> 1) * 64, wn = (w & 1) * 64;
  f32x4 acc[4][4] = {};
  int nk = Kd >> 5;
  stage_tile(A, m0, 0, Kd, SH);
  stage_tile(Bt, n0, 0, Kd, SH + 12288);
  stage_tile(A, m0, 32, Kd, SH + 4096);
  stage_tile(Bt, n0, 32, Kd, SH + 12288 + 4096);
  asm volatile("s_waitcnt vmcnt(4)" ::: "memory");
  __builtin_amdgcn_s_barrier();
  for (int kt = 0; kt < nk; ++kt) {
    if (kt + 2 < nk) {
      int bi = (kt + 2) % 3;
      stage_tile(A, m0, (kt + 2) * 32, Kd, SH + bi * 4096);
      stage_tile(Bt, n0, (kt + 2) * 32, Kd, SH + 12288 + bi * 4096);
    }
    const u16* Ac = SH + (kt % 3) * 4096;
    const u16* Bc = SH + 12288 + (kt % 3) * 4096;
    bf16x8 a[4], b[4];
    #pragma unroll
    for (int i = 0; i < 4; ++i) {
      int row = wm + i * 16 + lo;
      a[i] = *(const bf16x8*)&Ac[row * 32 + ((g ^ ((row >> 1) & 3)) << 3)];
    }
    #pragma unroll
    for (int j = 0; j < 4; ++j) {
      int row = wn + j * 16 + lo;
      b[j] = *(const bf16x8*)&Bc[row * 32 + ((g ^ ((row >> 1) & 3)) << 3)];
    }
    #pragma unroll
    for (int i = 0; i < 4; ++i)
      #pragma unroll
      for (int j = 0; j < 4; ++j)
        acc[i][j] = __builtin_amdgcn_mfma_f32_16x16x32_bf16(a[i], b[j], acc[i][j], 0, 0, 0);
    if (kt + 2 < nk) {
      asm volatile("s_waitcnt vmcnt(4)" ::: "memory");
    } else {
      asm volatile("s_waitcnt vmcnt(0)" ::: "memory");
    }
    __builtin_amdgcn_s_barrier();
  }
  #pragma unroll
  for (int j = 0; j < 4; ++j) {
    int n = n0 + wn + j * 16 + lo;
    float bv = bias[n];
    #pragma unroll
    for (int i = 0; i < 4; ++i) {
      #pragma unroll
      for (int r = 0; r < 4; ++r) {
        int m = m0 + wm + i * 16 + g * 4 + r;
        Cf[(size_t)m * N + n] = acc[i][j][r] + bv;
      }
    }
  }
}

// ---------------- flash attention (causal), split-K 8-wave blocks ----------------
// (champion config: best measured attn, ~85.5 us)
DEV void stage512(const u16* __restrict__ g, size_t rstride, u16* lds) {
  int t = threadIdx.x;            // 0..511, one 16B chunk per thread
  int r = t >> 3, pp = t & 7;
  int lg = pp ^ (r & 7);
  gload_lds16(g + (size_t)r * rstride + lg * 8, lds + (size_t)(t & ~63) * 8);
}

DEV void build_pfrags(const f32x16& s, bf16x8& f0, bf16x8& f1) {
  unsigned w0 = cvtpk(s[0], s[1]),  w1 = cvtpk(s[2], s[3]);
  unsigned w2 = cvtpk(s[4], s[5]),  w3 = cvtpk(s[6], s[7]);
  unsigned w4 = cvtpk(s[8], s[9]),  w5 = cvtpk(s[10], s[11]);
  unsigned w6 = cvtpk(s[12], s[13]), w7 = cvtpk(s[14], s[15]);
  pswap(w0, w2);
  pswap(w1, w3);
  pswap(w4, w6);
  pswap(w5, w7);
  union { unsigned u[4]; bf16x8 v; } t0, t1;
  t0.u[0] = w0; t0.u[1] = w1; t0.u[2] = w2; t0.u[3] = w3;
  t1.u[0] = w4; t1.u[1] = w5; t1.u[2] = w6; t1.u[3] = w7;
  f0 = t0.v; f1 = t1.v;
}

DEV void write_o(u16* __restrict__ O, size_t rowbase, const f32x16& o0,
                 const f32x16& o1, float L, int hf) {
  float inv = 1.0f / L;
  #pragma unroll
  for (int m = 0; m < 4; ++m) {
    uint2 v0, v1;
    v0.x = cvtpk(o0[4 * m] * inv,     o0[4 * m + 1] * inv);
    v0.y = cvtpk(o0[4 * m + 2] * inv, o0[4 * m + 3] * inv);
    *(uint2*)(O + rowbase + m * 8 + hf * 4) = v0;
    v1.x = cvtpk(o1[4 * m] * inv,     o1[4 * m + 1] * inv);
    v1.y = cvtpk(o1[4 * m + 2] * inv, o1[4 * m + 3] * inv);
    *(uint2*)(O + rowbase + 32 + m * 8 + hf * 4) = v1;
  }
}

__global__ __launch_bounds__(512) void attn_kernel(const u16* __restrict__ Q,
                                                   const u16* __restrict__ K,
                                                   const u16* __restrict__ Vt,
                                                   u16* __restrict__ O) {
  __shared__ __align__(16) u16 Ks[4][4096];
  __shared__ __align__(16) u16 Vs[4][4096];
  __shared__ float MLs[8][64][2];
  __shared__ float OSs[4][64][8];
  int p = blockIdx.y & 7;
  int bh = ((int)blockIdx.y >> 3) * 8 + (int)blockIdx.x;
  int b_ = bh >> 4, h = bh & 15;
  const u16* Qp = Q + (size_t)bh * Tt * HDd;
  const u16* Kp = K + (size_t)bh * Tt * HDd;
  const u16* Vp = Vt + (size_t)bh * HDd * Tt;
  int tid = threadIdx.x, w = tid >> 6, l = tid & 63;
  int wq = w & 3, grp = w >> 2;
  int lq = l & 31, hf = l >> 5;
  int JA = 15 - p, JB = p;
  int ntA = 2 * JA + 2;
  constexpr int ntT = 34;

  int q0 = 128 * JA + 32 * wq;
  int qrow = q0 + lq;
  int swz = lq & 7;

  bf16x8 aq[4];
  #pragma unroll
  for (int s = 0; s < 4; ++s)
    aq[s] = *(const bf16x8*)(Qp + (size_t)qrow * HDd + s * 16 + hf * 8);

  f32x16 o0 = {}, o1 = {};
  float M = -1e30f, L = 0.f;

  stage512(Kp, HDd, Ks[0]);
  stage512(Vp, Tt, Vs[0]);
  stage512(Kp + (size_t)64 * HDd, HDd, Ks[1]);
  stage512(Vp + 64, Tt, Vs[1]);
  asm volatile("s_waitcnt vmcnt(0)" ::: "memory");
  __builtin_amdgcn_s_barrier();

  int jB = ntA >> 1;
  for (int j = 0; j < ntT / 2; ++j) {
    int t2 = 2 * j + 2;
    if (t2 < ntT) {
      int kt2 = (t2 < ntA ? t2 : t2 - ntA) * 64;
      stage512(Kp + (size_t)kt2 * HDd, HDd, Ks[t2 & 3]);
      stage512(Vp + kt2, Tt, Vs[t2 & 3]);
      int t3 = t2 + 1;
      int kt3 = (t3 < ntA ? t3 : t3 - ntA) * 64;
      stage512(Kp + (size_t)kt3 * HDd, HDd, Ks[t3 & 3]);
      stage512(Vp + kt3, Tt, Vs[t3 & 3]);
    }
    if (j == jB) {
      MLs[w][l][0] = M; MLs[w][l][1] = L;
      asm volatile("s_waitcnt lgkmcnt(0)" ::: "memory");
      __builtin_amdgcn_s_barrier();
      float Mb = MLs[w ^ 4][l][0], Lb = MLs[w ^ 4][l][1];
      float Mstar = fmaxf(M, Mb);
      float ss = __builtin_amdgcn_exp2f(M - Mstar);
      float sb = __builtin_amdgcn_exp2f(Mb - Mstar);
      float Lm = L * ss + Lb * sb;
      #pragma unroll
      for (int r = 0; r < 16; ++r) { o0[r] *= ss; o1[r] *= ss; }
      #pragma unroll
      for (int c = 0; c < 4; ++c) {
        if (w >= 4) {
          #pragma unroll
          for (int k = 0; k < 8; ++k)
            OSs[wq][l][k] = (c < 2) ? o0[(c & 1) * 8 + k] : o1[(c & 1) * 8 + k];
        }
        asm volatile("s_waitcnt lgkmcnt(0)" ::: "memory");
        __builtin_amdgcn_s_barrier();
        if (w < 4) {
          #pragma unroll
          for (int k = 0; k < 8; ++k) {
            float v = OSs[wq][l][k];
            if (c < 2) o0[(c & 1) * 8 + k] += v; else o1[(c & 1) * 8 + k] += v;
          }
        }
        asm volatile("s_waitcnt lgkmcnt(0)" ::: "memory");
        __builtin_amdgcn_s_barrier();
      }
      if (w < 4) {
        size_t rbA = ((size_t)b_ * Tt + qrow) * Dd + h * HDd;
        write_o(O, rbA, o0, o1, Lm, hf);
      }
      #pragma unroll
      for (int r = 0; r < 16; ++r) { o0[r] = 0.f; o1[r] = 0.f; }
      M = -1e30f; L = 0.f;
      q0 = 128 * JB + 32 * wq;
      qrow = q0 + lq;
      #pragma unroll
      for (int s = 0; s < 4; ++s)
        aq[s] = *(const bf16x8*)(Qp + (size_t)qrow * HDd + s * 16 + hf * 8);
    }
    int myt = 2 * j + grp;
    int kt = (myt < ntA ? myt : myt - ntA) * 64;
    const u16* Kc = Ks[myt & 3];
    const u16* Vc = Vs[myt & 3];
    if (kt < q0 + 32) {
      f32x16 s0 = {}, s1 = {};
      __builtin_amdgcn_s_setprio(1);
      #pragma unroll
      for (int ds = 0; ds < 4; ++ds) {
        int slot = 2 * ds + hf;
        bf16x8 k0 = *(const bf16x8*)&Kc[lq * 64 + ((slot ^ swz) << 3)];
        bf16x8 k1 = *(const bf16x8*)&Kc[(32 + lq) * 64 + ((slot ^ swz) << 3)];
        s0 = __builtin_amdgcn_mfma_f32_32x32x16_bf16(k0, aq[ds], s0, 0, 0, 0);
        s1 = __builtin_amdgcn_mfma_f32_32x32x16_bf16(k1, aq[ds], s1, 0, 0, 0);
      }
      __builtin_amdgcn_s_setprio(0);
      if (kt + 63 > q0) {
        #pragma unroll
        for (int r = 0; r < 16; ++r) {
          int kg = kt + (r & 3) + 8 * (r >> 2) + 4 * hf;
          if (kg > qrow)      s0[r] = -INFINITY;
          if (kg + 32 > qrow) s1[r] = -INFINITY;
        }
      }
      float mx_[16];
      #pragma unroll
      for (int r = 0; r < 16; ++r) mx_[r] = fmaxf(s0[r], s1[r]);
      #pragma unroll
      for (int st = 8; st >= 1; st >>= 1)
        #pragma unroll
        for (int r = 0; r < 16; ++r) if (r < st) mx_[r] = fmaxf(mx_[r], mx_[r + st]);
      float mx = fmaxf(mx_[0], __shfl_xor(mx_[0], 32));
      float sc = 1.f;
      if (!__all(mx <= M + 8.f)) {
        float Mn = fmaxf(M, mx);
        sc = __builtin_amdgcn_exp2f(M - Mn);
        M = Mn;
        #pragma unroll
        for (int r = 0; r < 16; ++r) { o0[r] *= sc; o1[r] *= sc; }
      }
      #pragma unroll
      for (int r = 0; r < 16; ++r) {
        s0[r] = __builtin_amdgcn_exp2f(s0[r] - M);
        s1[r] = __builtin_amdgcn_exp2f(s1[r] - M);
      }
      float ls_[16];
      #pragma unroll
      for (int r = 0; r < 16; ++r) ls_[r] = s0[r] + s1[r];
      #pragma unroll
      for (int st = 8; st >= 1; st >>= 1)
        #pragma unroll
        for (int r = 0; r < 16; ++r) if (r < st) ls_[r] += ls_[r + st];
      float ls = ls_[0] + __shfl_xor(ls_[0], 32);
      L = L * sc + ls;
      bf16x8 pf0, pf1, pf2, pf3;
      build_pfrags(s0, pf0, pf1);
      build_pfrags(s1, pf2, pf3);
      __builtin_amdgcn_s_setprio(1);
      #pragma unroll
      for (int ks = 0; ks < 4; ++ks) {
        int slot = 2 * ks + hf;
        bf16x8 v0 = *(const bf16x8*)&Vc[lq * 64 + ((slot ^ swz) << 3)];
        bf16x8 v1 = *(const bf16x8*)&Vc[(32 + lq) * 64 + ((slot ^ swz) << 3)];
        bf16x8 pf = (ks == 0) ? pf0 : (ks == 1) ? pf1 : (ks == 2) ? pf2 : pf3;
        o0 = __builtin_amdgcn_mfma_f32_32x32x16_bf16(v0, pf, o0, 0, 0, 0);
        o1 = __builtin_amdgcn_mfma_f32_32x32x16_bf16(v1, pf, o1, 0, 0, 0);
      }
      __builtin_amdgcn_s_setprio(0);
    }
    asm volatile("s_waitcnt vmcnt(0)" ::: "memory");
    __builtin_amdgcn_s_barrier();
  }

  MLs[w][l][0] = M; MLs[w][l][1] = L;
  asm volatile("s_waitcnt lgkmcnt(0)" ::: "memory");
  __builtin_amdgcn_s_barrier();
  float Mb = MLs[w ^ 4][l][0], Lb = MLs[w ^ 4][l][1];
  float Mstar = fmaxf(M, Mb);
  float ss = __builtin_amdgcn_exp2f(M - Mstar);
  float sb = __builtin_amdgcn_exp2f(Mb - Mstar);
  float Lm = L * ss + Lb * sb;
  #pragma unroll
  for (int r = 0; r < 16; ++r) { o0[r] *= ss; o1[r] *= ss; }
  #pragma unroll
  for (int c = 0; c < 4; ++c) {
    if (w >= 4) {
      #pragma unroll
      for (int k = 0; k < 8; ++k)
        OSs[wq][l][k] = (c < 2) ? o0[(c & 1) * 8 + k] : o1[(c & 1) * 8 + k];
    }
    asm volatile("s_waitcnt lgkmcnt(0)" ::: "memory");
    __builtin_amdgcn_s_barrier();
    if (w < 4) {
      #pragma unroll
      for (int k = 0; k < 8; ++k) {
        float v = OSs[wq][l][k];
        if (c < 2) o0[(c & 1) * 8 + k] += v; else o1[(c & 1) * 8 + k] += v;
      }
    }
    asm volatile("s_waitcnt lgkmcnt(0)" ::: "memory");
    __builtin_amdgcn_s_barrier();
  }
  if (w < 4) {
    size_t rbB = ((size_t)b_ * Tt + qrow) * Dd + h * HDd;
    write_o(O, rbB, o0, o1, Lm, hf);
  }
}

extern "C" void kernel_launch(void* const* d_in, const int* in_sizes, int n_in,
                              void* d_out, int out_size, void* d_ws, size_t ws_size,
                              hipStream_t stream) {
  const float* x    = (const float*)d_in[0];
  const float* Wqkv = (const float*)d_in[1];
  const float* bqkv = (const float*)d_in[2];
  const float* Wout = (const float*)d_in[3];
  const float* bout = (const float*)d_in[4];
  float* out = (float*)d_out;
  char* ws = (char*)d_ws;

  u16* xb    = (u16*)(ws + 0);           // 16,777,216 (aliased by Ob)
  u16* Ob    = (u16*)(ws + 0);           // alias xb
  u16* Wqkvt = (u16*)(ws + 16777216);    //  6,291,456
  u16* Woutt = (u16*)(ws + 23068672);    //  2,097,152
  u16* Qb    = (u16*)(ws + 25165824);    // 16,777,216
  u16* Kb    = (u16*)(ws + 41943040);    // 16,777,216
  u16* Vtb   = (u16*)(ws + 58720256);    // 16,777,216

  cast_x_kernel<<<4096, 256, 0, stream>>>(x, xb, (MM * Dd) / 8);
  wcast_t_kernel<<<dim3(96, 32), 256, 0, stream>>>(Wqkv, Wqkvt, Dd, 3 * Dd);
  wcast_t_kernel<<<dim3(32, 32), 256, 0, stream>>>(Wout, Woutt, Dd, Dd);
  gemm_qkv_kernel<<<dim3(12, 32), 512, 0, stream>>>(
      xb, Wqkvt, bqkv, Qb, Kb, Vtb, MM, 3 * Dd, Dd);
  attn_kernel<<<dim3(8, 64), 512, 0, stream>>>(Qb, Kb, Vtb, Ob);
  gemm_out_kernel<<<dim3(8, 64), 256, 0, stream>>>(
      Ob, Woutt, bout, out, MM, Dd, Dd);
}

// Round 20
// 172.245 us; speedup vs baseline: 1.0430x; 1.0430x over previous
//
#include <hip/hip_runtime.h>

typedef unsigned short u16;
typedef __bf16 bf16x8 __attribute__((ext_vector_type(8)));
typedef float f32x4 __attribute__((ext_vector_type(4)));
typedef float f32x16 __attribute__((ext_vector_type(16)));

#define DEV __device__ __forceinline__

constexpr int Bb = 4, Tt = 2048, Dd = 1024, Hh = 16, HDd = 64;
constexpr int MM = Bb * Tt;        // 8192
constexpr float QSCALE = 0.125f * 1.4426950408889634f;  // 1/sqrt(64) * log2(e)

DEV u16 f2bf(float f) {
  unsigned u = __float_as_uint(f);
  u += 0x7fffu + ((u >> 16) & 1u);   // RNE
  return (u16)(u >> 16);
}

DEV unsigned cvtpk(float a, float b) {   // bf16(a) in lo16, bf16(b) in hi16
  unsigned r;
  asm("v_cvt_pk_bf16_f32 %0, %1, %2" : "=v"(r) : "v"(a), "v"(b));
  return r;
}

DEV void pswap(unsigned& a, unsigned& b) {  // half-exchange across lane-32 split
  // NOTE: callers must pass values that are NOT provably equal, else the
  // compiler may alias a,b into one VGPR and the swap degenerates (R4 NaN).
  asm("v_permlane32_swap_b32 %0, %1" : "+v"(a), "+v"(b));
}

DEV void gload_lds16(const u16* g, u16* l) {
  __builtin_amdgcn_global_load_lds(
      (const __attribute__((address_space(1))) void*)g,
      (__attribute__((address_space(3))) void*)l, 16, 0, 0);
}

// ---------------- cast x -> bf16 ----------------
__global__ __launch_bounds__(256) void cast_x_kernel(const float* __restrict__ in,
                                                     u16* __restrict__ out, int n8) {
  int i = blockIdx.x * 256 + threadIdx.x;
  if (i >= n8) return;
  const float4* p = (const float4*)in + (size_t)i * 2;
  float4 v0 = p[0], v1 = p[1];
  union { u16 u[8]; uint4 v; } t;
  t.u[0] = f2bf(v0.x); t.u[1] = f2bf(v0.y); t.u[2] = f2bf(v0.z); t.u[3] = f2bf(v0.w);
  t.u[4] = f2bf(v1.x); t.u[5] = f2bf(v1.y); t.u[6] = f2bf(v1.z); t.u[7] = f2bf(v1.w);
  ((uint4*)out)[i] = t.v;
}

// ---------- cast + transpose weights: [K][N] f32 -> [N][K] bf16 ----------
__global__ __launch_bounds__(256) void wcast_t_kernel(const float* __restrict__ in,
                                                      u16* __restrict__ out, int K, int N) {
  __shared__ float tile[32][33];
  int n0 = blockIdx.x * 32, k0 = blockIdx.y * 32;
  int tx = threadIdx.x & 31, ty = threadIdx.x >> 5;
  #pragma unroll
  for (int yy = ty; yy < 32; yy += 8)
    tile[yy][tx] = in[(size_t)(k0 + yy) * N + n0 + tx];
  __syncthreads();
  #pragma unroll
  for (int yy = ty; yy < 32; yy += 8)
    out[(size_t)(n0 + yy) * K + k0 + tx] = f2bf(tile[tx][yy]);
}

// ======== 128(M)x256(N) QKV GEMM: 8 waves (2x4), per-wave 64x64, 16x16 MFMA ========
// Triple-buffered BK=32 with counted vmcnt: 3 loads/thread/K-step (1 A + 2 B);
// end-of-iter vmcnt(3) keeps the newest batch (tile kt+2) in flight, all older
// batches (incl. tile kt+1) complete. LDS 72KB. Epilogue = proven 64x64 patch
// code, run as two 4-wave rounds.
DEV void stageA128(const u16* __restrict__ src, int row0, int k0, int ld, u16* lds) {
  int t = threadIdx.x;              // 512 chunks of 16B, 1 per thread
  int r = t >> 2, slot = t & 3;
  int c = (slot ^ ((r >> 1) & 3)) << 3;
  gload_lds16(src + (size_t)(row0 + r) * ld + k0 + c, lds + (size_t)(t & ~63) * 8);
}
DEV void stageB256(const u16* __restrict__ src, int row0, int k0, int ld, u16* lds) {
  int t = threadIdx.x;              // 1024 chunks, 2 per thread
  #pragma unroll
  for (int j = 0; j < 2; ++j) {
    int e = j * 512 + t;
    int r = e >> 2, slot = e & 3;
    int c = (slot ^ ((r >> 1) & 3)) << 3;
    gload_lds16(src + (size_t)(row0 + r) * ld + k0 + c,
                lds + (size_t)(j * 512 + (t & ~63)) * 8);
  }
}

__global__ __launch_bounds__(512, 4) void gemm_qkv_kernel(
    const u16* __restrict__ A, const u16* __restrict__ Bt,
    const float* __restrict__ bias,
    u16* __restrict__ Qb, u16* __restrict__ Kb, u16* __restrict__ Vtb,
    int M, int N, int Kd) {
  // A bufs: SH + bi*4096 (3 x 8KB); B bufs: SH + 12288 + bi*8192 (3 x 16KB).
  __shared__ __align__(16) u16 SH[36864];   // 72 KB
  int nx = N >> 8;                           // 12
  int bid = blockIdx.y * nx + blockIdx.x;
  int nwg = (M >> 7) * nx;                   // 768 (%8==0)
  int swz = (bid & 7) * (nwg >> 3) + (bid >> 3);
  int m0 = (swz / nx) * 128, n0 = (swz % nx) * 256;

  int tid = threadIdx.x, l = tid & 63, w = tid >> 6;
  int lo = l & 15, g = l >> 4;
  int wm = (w >> 2) * 64, wn = (w & 3) * 64;   // per-wave 64x64
  f32x4 acc[4][4] = {};
  int nk = Kd >> 5;                          // 32
  // prologue: stage k-tiles 0 and 1 (3 loads each), wait tile0 only.
  stageA128(A, m0, 0, Kd, SH);
  stageB256(Bt, n0, 0, Kd, SH + 12288);
  stageA128(A, m0, 32, Kd, SH + 4096);
  stageB256(Bt, n0, 32, Kd, SH + 12288 + 8192);
  asm volatile("s_waitcnt vmcnt(3)" ::: "memory");
  __builtin_amdgcn_s_barrier();
  for (int kt = 0; kt < nk; ++kt) {
    if (kt + 2 < nk) {
      int bi = (kt + 2) % 3;
      stageA128(A, m0, (kt + 2) * 32, Kd, SH + bi * 4096);
      stageB256(Bt, n0, (kt + 2) * 32, Kd, SH + 12288 + bi * 8192);
    }
    const u16* Ac = SH + (kt % 3) * 4096;
    const u16* Bc = SH + 12288 + (kt % 3) * 8192;
    bf16x8 a[4], b[4];
    #pragma unroll
    for (int i = 0; i < 4; ++i) {
      int row = wm + i * 16 + lo;
      a[i] = *(const bf16x8*)&Ac[row * 32 + ((g ^ ((row >> 1) & 3)) << 3)];
    }
    #pragma unroll
    for (int j = 0; j < 4; ++j) {
      int row = wn + j * 16 + lo;
      b[j] = *(const bf16x8*)&Bc[row * 32 + ((g ^ ((row >> 1) & 3)) << 3)];
    }
    __builtin_amdgcn_s_setprio(1);
    #pragma unroll
    for (int i = 0; i < 4; ++i)
      #pragma unroll
      for (int j = 0; j < 4; ++j)
        acc[i][j] = __builtin_amdgcn_mfma_f32_16x16x32_bf16(a[i], b[j], acc[i][j], 0, 0, 0);
    __builtin_amdgcn_s_setprio(0);
    if (kt + 2 < nk) {
      asm volatile("s_waitcnt vmcnt(3)" ::: "memory");
    } else {
      asm volatile("s_waitcnt vmcnt(0)" ::: "memory");
    }
    __builtin_amdgcn_s_barrier();
  }
  // ---- epilogue: two rounds of 4 waves; per-wave 8KB patch at SH + (w&3)*4096 ----
  #pragma unroll
  for (int round = 0; round < 2; ++round) {
    if ((w >> 2) == round) {
      u16* ep = SH + (w & 3) * 4096;
      int nblk = n0 + wn;
      int hh = nblk / 192, which = (nblk % 192) >> 6;
      int mblk = m0 + wm;
      int b_ = mblk >> 11, t0 = mblk & (Tt - 1);
      if (which == 2) {
        // V: patch[d][t_local] (transposed) -> Vt[bh][d][t]
        #pragma unroll
        for (int j = 0; j < 4; ++j) {
          float bv = bias[nblk + j * 16 + lo];
          int rowp = j * 16 + lo;          // d
          #pragma unroll
          for (int i = 0; i < 4; ++i) {
            int slotp = i * 2 + (g >> 1);  // (i*16+g*4+r)>>3
            #pragma unroll
            for (int r = 0; r < 4; ++r) {
              ep[rowp * 64 + ((slotp ^ (rowp & 7)) << 3) + (g & 1) * 4 + r] =
                  f2bf(acc[i][j][r] + bv);
            }
          }
        }
        asm volatile("s_waitcnt lgkmcnt(0)" ::: "memory");
        u16* dst = Vtb + (size_t)(b_ * Hh + hh) * HDd * Tt + t0;
        #pragma unroll
        for (int s = 0; s < 8; ++s) {
          int row = s * 8 + (l >> 3);      // d
          int phys = ((l & 7) ^ (row & 7)) << 3;
          uint4 v = *(const uint4*)&ep[row * 64 + phys];
          *(uint4*)(dst + (size_t)row * Tt + (l & 7) * 8) = v;
        }
      } else {
        float qs = (which == 0) ? QSCALE : 1.0f;
        #pragma unroll
        for (int j = 0; j < 4; ++j) {
          float bv = bias[nblk + j * 16 + lo];
          int slot = j * 2 + (lo >> 3);
          #pragma unroll
          for (int i = 0; i < 4; ++i) {
            #pragma unroll
            for (int r = 0; r < 4; ++r) {
              int lrow = i * 16 + g * 4 + r;
              ep[lrow * 64 + ((slot ^ (lrow & 7)) << 3) + (lo & 7)] =
                  f2bf((acc[i][j][r] + bv) * qs);
            }
          }
        }
        asm volatile("s_waitcnt lgkmcnt(0)" ::: "memory");
        u16* dst = (which == 0) ? Qb : Kb;
        dst += ((size_t)(b_ * Hh + hh) * Tt + t0) * HDd;
        #pragma unroll
        for (int s = 0; s < 8; ++s) {
          int row = s * 8 + (l >> 3);
          int phys = ((l & 7) ^ (row & 7)) << 3;
          uint4 v = *(const uint4*)&ep[row * 64 + phys];
          *(uint4*)(dst + row * 64 + (l & 7) * 8) = v;
        }
      }
    }
    __syncthreads();
  }
}

// ---------------- 128x128 GEMM (out-proj): A[M][K] * Bt[N][K] -> f32 ----------------
DEV void stage_tile(const u16* __restrict__ src, int row0, int k0, int ld, u16* lds) {
  int t = threadIdx.x, w = t >> 6;
  #pragma unroll
  for (int j = 0; j < 2; ++j) {
    int e = (j * 256 + t) * 8;
    int r = e >> 5;
    int slot = (e >> 3) & 3;
    int c = (slot ^ ((r >> 1) & 3)) << 3;
    gload_lds16(src + (size_t)(row0 + r) * ld + k0 + c, lds + j * 2048 + w * 512);
  }
}

__global__ __launch_bounds__(256) void gemm_out_kernel(
    const u16* __restrict__ A, const u16* __restrict__ Bt,
    const float* __restrict__ bias, float* __restrict__ Cf,
    int M, int N, int Kd) {
  __shared__ __align__(16) u16 SH[24576];
  int nx = N >> 7;
  int bid = blockIdx.y * nx + blockIdx.x;
  int nwg = (M >> 7) * nx;
  int swz = (bid & 7) * (nwg >> 3) + (bid >> 3);
  int m0 = (swz / nx) * 128, n0 = (swz % nx) * 128;

  int tid = threadIdx.x, l = tid & 63, w = tid >> 6;
  int lo = l & 15, g = l >> 4;
  int wm = (w >> 1) * 64, wn = (w & 1) * 64;
  f32x4 acc[4][4] = {};
  int nk = Kd >> 5;
  stage_tile(A, m0, 0, Kd, SH);
  stage_tile(Bt, n0, 0, Kd, SH + 12288);
  stage_tile(A, m0, 32, Kd, SH + 4096);
  stage_tile(Bt, n0, 32, Kd, SH + 12288 + 4096);
  asm volatile("s_waitcnt vmcnt(4)" ::: "memory");
  __builtin_amdgcn_s_barrier();
  for (int kt = 0; kt < nk; ++kt) {
    if (kt + 2 < nk) {
      int bi = (kt + 2) % 3;
      stage_tile(A, m0, (kt + 2) * 32, Kd, SH + bi * 4096);
      stage_tile(Bt, n0, (kt + 2) * 32, Kd, SH + 12288 + bi * 4096);
    }
    const u16* Ac = SH + (kt % 3) * 4096;
    const u16* Bc = SH + 12288 + (kt % 3) * 4096;
    bf16x8 a[4], b[4];
    #pragma unroll
    for (int i = 0; i < 4; ++i) {
      int row = wm + i * 16 + lo;
      a[i] = *(const bf16x8*)&Ac[row * 32 + ((g ^ ((row >> 1) & 3)) << 3)];
    }
    #pragma unroll
    for (int j = 0; j < 4; ++j) {
      int row = wn + j * 16 + lo;
      b[j] = *(const bf16x8*)&Bc[row * 32 + ((g ^ ((row >> 1) & 3)) << 3)];
    }
    #pragma unroll
    for (int i = 0; i < 4; ++i)
      #pragma unroll
      for (int j = 0; j < 4; ++j)
        acc[i][j] = __builtin_amdgcn_mfma_f32_16x16x32_bf16(a[i], b[j], acc[i][j], 0, 0, 0);
    if (kt + 2 < nk) {
      asm volatile("s_waitcnt vmcnt(4)" ::: "memory");
    } else {
      asm volatile("s_waitcnt vmcnt(0)" ::: "memory");
    }
    __builtin_amdgcn_s_barrier();
  }
  #pragma unroll
  for (int j = 0; j < 4; ++j) {
    int n = n0 + wn + j * 16 + lo;
    float bv = bias[n];
    #pragma unroll
    for (int i = 0; i < 4; ++i) {
      #pragma unroll
      for (int r = 0; r < 4; ++r) {
        int m = m0 + wm + i * 16 + g * 4 + r;
        Cf[(size_t)m * N + n] = acc[i][j][r] + bv;
      }
    }
  }
}

// ---------------- flash attention (causal), split-K 8-wave blocks ----------------
// grid (8,64), 512 threads = 8 waves; id%8 == bh%8 (XCD locality). Paired
// q-blocks JA=15-p / JB=p. Waves 0-3 own 32 q-rows each and process EVEN
// k-tiles; waves 4-7 duplicate the q-rows and process ODD k-tiles (17/wave).
// Two-way flash merge (M/L + chunked O via LDS) at pass boundary and at end.
DEV void stage512(const u16* __restrict__ g, size_t rstride, u16* lds) {
  int t = threadIdx.x;            // 0..511, one 16B chunk per thread
  int r = t >> 3, pp = t & 7;
  int lg = pp ^ (r & 7);
  gload_lds16(g + (size_t)r * rstride + lg * 8, lds + (size_t)(t & ~63) * 8);
}

DEV void build_pfrags(const f32x16& s, bf16x8& f0, bf16x8& f1) {
  unsigned w0 = cvtpk(s[0], s[1]),  w1 = cvtpk(s[2], s[3]);
  unsigned w2 = cvtpk(s[4], s[5]),  w3 = cvtpk(s[6], s[7]);
  unsigned w4 = cvtpk(s[8], s[9]),  w5 = cvtpk(s[10], s[11]);
  unsigned w6 = cvtpk(s[12], s[13]), w7 = cvtpk(s[14], s[15]);
  pswap(w0, w2);
  pswap(w1, w3);
  pswap(w4, w6);
  pswap(w5, w7);
  union { unsigned u[4]; bf16x8 v; } t0, t1;
  t0.u[0] = w0; t0.u[1] = w1; t0.u[2] = w2; t0.u[3] = w3;
  t1.u[0] = w4; t1.u[1] = w5; t1.u[2] = w6; t1.u[3] = w7;
  f0 = t0.v; f1 = t1.v;
}

DEV void write_o(u16* __restrict__ O, size_t rowbase, const f32x16& o0,
                 const f32x16& o1, float L, int hf) {
  float inv = 1.0f / L;
  #pragma unroll
  for (int m = 0; m < 4; ++m) {
    uint2 v0, v1;
    v0.x = cvtpk(o0[4 * m] * inv,     o0[4 * m + 1] * inv);
    v0.y = cvtpk(o0[4 * m + 2] * inv, o0[4 * m + 3] * inv);
    *(uint2*)(O + rowbase + m * 8 + hf * 4) = v0;
    v1.x = cvtpk(o1[4 * m] * inv,     o1[4 * m + 1] * inv);
    v1.y = cvtpk(o1[4 * m + 2] * inv, o1[4 * m + 3] * inv);
    *(uint2*)(O + rowbase + 32 + m * 8 + hf * 4) = v1;
  }
}

__global__ __launch_bounds__(512) void attn_kernel(const u16* __restrict__ Q,
                                                   const u16* __restrict__ K,
                                                   const u16* __restrict__ Vt,
                                                   u16* __restrict__ O) {
  __shared__ __align__(16) u16 Ks[4][4096];
  __shared__ __align__(16) u16 Vs[4][4096];
  __shared__ float MLs[8][64][2];
  __shared__ float OSs[4][64][8];
  int p = blockIdx.y & 7;
  int bh = ((int)blockIdx.y >> 3) * 8 + (int)blockIdx.x;
  int b_ = bh >> 4, h = bh & 15;
  const u16* Qp = Q + (size_t)bh * Tt * HDd;
  const u16* Kp = K + (size_t)bh * Tt * HDd;
  const u16* Vp = Vt + (size_t)bh * HDd * Tt;
  int tid = threadIdx.x, w = tid >> 6, l = tid & 63;
  int wq = w & 3, grp = w >> 2;
  int lq = l & 31, hf = l >> 5;
  int JA = 15 - p, JB = p;
  int ntA = 2 * JA + 2;
  constexpr int ntT = 34;

  int q0 = 128 * JA + 32 * wq;
  int qrow = q0 + lq;
  int swz = lq & 7;

  bf16x8 aq[4];
  #pragma unroll
  for (int s = 0; s < 4; ++s)
    aq[s] = *(const bf16x8*)(Qp + (size_t)qrow * HDd + s * 16 + hf * 8);

  f32x16 o0 = {}, o1 = {};
  float M = -1e30f, L = 0.f;

  stage512(Kp, HDd, Ks[0]);
  stage512(Vp, Tt, Vs[0]);
  stage512(Kp + (size_t)64 * HDd, HDd, Ks[1]);
  stage512(Vp + 64, Tt, Vs[1]);
  asm volatile("s_waitcnt vmcnt(0)" ::: "memory");
  __builtin_amdgcn_s_barrier();

  int jB = ntA >> 1;
  for (int j = 0; j < ntT / 2; ++j) {
    int t2 = 2 * j + 2;
    if (t2 < ntT) {
      int kt2 = (t2 < ntA ? t2 : t2 - ntA) * 64;
      stage512(Kp + (size_t)kt2 * HDd, HDd, Ks[t2 & 3]);
      stage512(Vp + kt2, Tt, Vs[t2 & 3]);
      int t3 = t2 + 1;
      int kt3 = (t3 < ntA ? t3 : t3 - ntA) * 64;
      stage512(Kp + (size_t)kt3 * HDd, HDd, Ks[t3 & 3]);
      stage512(Vp + kt3, Tt, Vs[t3 & 3]);
    }
    if (j == jB) {
      MLs[w][l][0] = M; MLs[w][l][1] = L;
      asm volatile("s_waitcnt lgkmcnt(0)" ::: "memory");
      __builtin_amdgcn_s_barrier();
      float Mb = MLs[w ^ 4][l][0], Lb = MLs[w ^ 4][l][1];
      float Mstar = fmaxf(M, Mb);
      float ss = __builtin_amdgcn_exp2f(M - Mstar);
      float sb = __builtin_amdgcn_exp2f(Mb - Mstar);
      float Lm = L * ss + Lb * sb;
      #pragma unroll
      for (int r = 0; r < 16; ++r) { o0[r] *= ss; o1[r] *= ss; }
      #pragma unroll
      for (int c = 0; c < 4; ++c) {
        if (w >= 4) {
          #pragma unroll
          for (int k = 0; k < 8; ++k)
            OSs[wq][l][k] = (c < 2) ? o0[(c & 1) * 8 + k] : o1[(c & 1) * 8 + k];
        }
        asm volatile("s_waitcnt lgkmcnt(0)" ::: "memory");
        __builtin_amdgcn_s_barrier();
        if (w < 4) {
          #pragma unroll
          for (int k = 0; k < 8; ++k) {
            float v = OSs[wq][l][k];
            if (c < 2) o0[(c & 1) * 8 + k] += v; else o1[(c & 1) * 8 + k] += v;
          }
        }
        asm volatile("s_waitcnt lgkmcnt(0)" ::: "memory");
        __builtin_amdgcn_s_barrier();
      }
      if (w < 4) {
        size_t rbA = ((size_t)b_ * Tt + qrow) * Dd + h * HDd;
        write_o(O, rbA, o0, o1, Lm, hf);
      }
      #pragma unroll
      for (int r = 0; r < 16; ++r) { o0[r] = 0.f; o1[r] = 0.f; }
      M = -1e30f; L = 0.f;
      q0 = 128 * JB + 32 * wq;
      qrow = q0 + lq;
      #pragma unroll
      for (int s = 0; s < 4; ++s)
        aq[s] = *(const bf16x8*)(Qp + (size_t)qrow * HDd + s * 16 + hf * 8);
    }
    int myt = 2 * j + grp;
    int kt = (myt < ntA ? myt : myt - ntA) * 64;
    const u16* Kc = Ks[myt & 3];
    const u16* Vc = Vs[myt & 3];
    if (kt < q0 + 32) {
      f32x16 s0 = {}, s1 = {};
      __builtin_amdgcn_s_setprio(1);
      #pragma unroll
      for (int ds = 0; ds < 4; ++ds) {
        int slot = 2 * ds + hf;
        bf16x8 k0 = *(const bf16x8*)&Kc[lq * 64 + ((slot ^ swz) << 3)];
        bf16x8 k1 = *(const bf16x8*)&Kc[(32 + lq) * 64 + ((slot ^ swz) << 3)];
        s0 = __builtin_amdgcn_mfma_f32_32x32x16_bf16(k0, aq[ds], s0, 0, 0, 0);
        s1 = __builtin_amdgcn_mfma_f32_32x32x16_bf16(k1, aq[ds], s1, 0, 0, 0);
      }
      __builtin_amdgcn_s_setprio(0);
      if (kt + 63 > q0) {
        #pragma unroll
        for (int r = 0; r < 16; ++r) {
          int kg = kt + (r & 3) + 8 * (r >> 2) + 4 * hf;
          if (kg > qrow)      s0[r] = -INFINITY;
          if (kg + 32 > qrow) s1[r] = -INFINITY;
        }
      }
      float mx_[16];
      #pragma unroll
      for (int r = 0; r < 16; ++r) mx_[r] = fmaxf(s0[r], s1[r]);
      #pragma unroll
      for (int st = 8; st >= 1; st >>= 1)
        #pragma unroll
        for (int r = 0; r < 16; ++r) if (r < st) mx_[r] = fmaxf(mx_[r], mx_[r + st]);
      float mx = fmaxf(mx_[0], __shfl_xor(mx_[0], 32));
      float sc = 1.f;
      if (!__all(mx <= M + 8.f)) {
        float Mn = fmaxf(M, mx);
        sc = __builtin_amdgcn_exp2f(M - Mn);
        M = Mn;
        #pragma unroll
        for (int r = 0; r < 16; ++r) { o0[r] *= sc; o1[r] *= sc; }
      }
      #pragma unroll
      for (int r = 0; r < 16; ++r) {
        s0[r] = __builtin_amdgcn_exp2f(s0[r] - M);
        s1[r] = __builtin_amdgcn_exp2f(s1[r] - M);
      }
      float ls_[16];
      #pragma unroll
      for (int r = 0; r < 16; ++r) ls_[r] = s0[r] + s1[r];
      #pragma unroll
      for (int st = 8; st >= 1; st >>= 1)
        #pragma unroll
        for (int r = 0; r < 16; ++r) if (r < st) ls_[r] += ls_[r + st];
      float ls = ls_[0] + __shfl_xor(ls_[0], 32);
      L = L * sc + ls;
      bf16x8 pf0, pf1, pf2, pf3;
      build_pfrags(s0, pf0, pf1);
      build_pfrags(s1, pf2, pf3);
      __builtin_amdgcn_s_setprio(1);
      #pragma unroll
      for (int ks = 0; ks < 4; ++ks) {
        int slot = 2 * ks + hf;
        bf16x8 v0 = *(const bf16x8*)&Vc[lq * 64 + ((slot ^ swz) << 3)];
        bf16x8 v1 = *(const bf16x8*)&Vc[(32 + lq) * 64 + ((slot ^ swz) << 3)];
        bf16x8 pf = (ks == 0) ? pf0 : (ks == 1) ? pf1 : (ks == 2) ? pf2 : pf3;
        o0 = __builtin_amdgcn_mfma_f32_32x32x16_bf16(v0, pf, o0, 0, 0, 0);
        o1 = __builtin_amdgcn_mfma_f32_32x32x16_bf16(v1, pf, o1, 0, 0, 0);
      }
      __builtin_amdgcn_s_setprio(0);
    }
    asm volatile("s_waitcnt vmcnt(0)" ::: "memory");
    __builtin_amdgcn_s_barrier();
  }

  MLs[w][l][0] = M; MLs[w][l][1] = L;
  asm volatile("s_waitcnt lgkmcnt(0)" ::: "memory");
  __builtin_amdgcn_s_barrier();
  float Mb = MLs[w ^ 4][l][0], Lb = MLs[w ^ 4][l][1];
  float Mstar = fmaxf(M, Mb);
  float ss = __builtin_amdgcn_exp2f(M - Mstar);
  float sb = __builtin_amdgcn_exp2f(Mb - Mstar);
  float Lm = L * ss + Lb * sb;
  #pragma unroll
  for (int r = 0; r < 16; ++r) { o0[r] *= ss; o1[r] *= ss; }
  #pragma unroll
  for (int c = 0; c < 4; ++c) {
    if (w >= 4) {
      #pragma unroll
      for (int k = 0; k < 8; ++k)
        OSs[wq][l][k] = (c < 2) ? o0[(c & 1) * 8 + k] : o1[(c & 1) * 8 + k];
    }
    asm volatile("s_waitcnt lgkmcnt(0)" ::: "memory");
    __builtin_amdgcn_s_barrier();
    if (w < 4) {
      #pragma unroll
      for (int k = 0; k < 8; ++k) {
        float v = OSs[wq][l][k];
        if (c < 2) o0[(c & 1) * 8 + k] += v; else o1[(c & 1) * 8 + k] += v;
      }
    }
    asm volatile("s_waitcnt lgkmcnt(0)" ::: "memory");
    __builtin_amdgcn_s_barrier();
  }
  if (w < 4) {
    size_t rbB = ((size_t)b_ * Tt + qrow) * Dd + h * HDd;
    write_o(O, rbB, o0, o1, Lm, hf);
  }
}

extern "C" void kernel_launch(void* const* d_in, const int* in_sizes, int n_in,
                              void* d_out, int out_size, void* d_ws, size_t ws_size,
                              hipStream_t stream) {
  const float* x    = (const float*)d_in[0];
  const float* Wqkv = (const float*)d_in[1];
  const float* bqkv = (const float*)d_in[2];
  const float* Wout = (const float*)d_in[3];
  const float* bout = (const float*)d_in[4];
  float* out = (float*)d_out;
  char* ws = (char*)d_ws;

  u16* xb    = (u16*)(ws + 0);           // 16,777,216 (aliased by Ob)
  u16* Ob    = (u16*)(ws + 0);           // alias xb
  u16* Wqkvt = (u16*)(ws + 16777216);    //  6,291,456
  u16* Woutt = (u16*)(ws + 23068672);    //  2,097,152
  u16* Qb    = (u16*)(ws + 25165824);    // 16,777,216
  u16* Kb    = (u16*)(ws + 41943040);    // 16,777,216
  u16* Vtb   = (u16*)(ws + 58720256);    // 16,777,216

  cast_x_kernel<<<4096, 256, 0, stream>>>(x, xb, (MM * Dd) / 8);
  wcast_t_kernel<<<dim3(96, 32), 256, 0, stream>>>(Wqkv, Wqkvt, Dd, 3 * Dd);
  wcast_t_kernel<<<dim3(32, 32), 256, 0, stream>>>(Wout, Woutt, Dd, Dd);
  gemm_qkv_kernel<<<dim3(12, 64), 512, 0, stream>>>(
      xb, Wqkvt, bqkv, Qb, Kb, Vtb, MM, 3 * Dd, Dd);
  attn_kernel<<<dim3(8, 64), 512, 0, stream>>>(Qb, Kb, Vtb, Ob);
  gemm_out_kernel<<<dim3(8, 64), 256, 0, stream>>>(
      Ob, Woutt, bout, out, MM, Dd, Dd);
}